// Round 14
// baseline (853.678 us; speedup 1.0000x reference)
//
#include <hip/hip_runtime.h>
#include <hip/hip_fp16.h>
#include <math.h>
#include <float.h>

// ---------------------------------------------------------------------------
// GCN on MI355X. N=50000, E=1.6M, widths 128 -> 64 (x8) -> 4.
// R13 structure (best: 845us) + 16-bit CSR indices (n<65536): halves fill's
// scattered-write traffic and the aggs' csr stream, and packs index loads as
// scalar dwords (2 edges per s_load). Each (dst,src_tile) cell padded to an
// even edge count with dummy index n -> hs/h4 row n is zeroed, contributing
// exact +0; row starts stay even so pair loads are aligned.
// Agg inner loop otherwise identical to R13 (wave/node, scalar idx loads).
// Activations fp16 (fp32 accum), dinv folded into epilogues. Final layer:
// GEMM to 4 then 4-wide agg. Softmax over node axis.
// ---------------------------------------------------------------------------

#define NPART 8
#define BPP   104     // blocks per partition for fill
#define T     4       // src tiles

typedef float f4 __attribute__((ext_vector_type(4)));

// ---------------- (dst, src_tile) histogram ----------------

__global__ __launch_bounds__(256) void k_count(const int* __restrict__ src,
                                               const int* __restrict__ dst,
                                               unsigned* __restrict__ cnt,
                                               int E, int chunkS) {
    int e = blockIdx.x * 256 + threadIdx.x;
    if (e >= E) return;
    int d = dst[e];
    int t = src[e] / chunkS;
    atomicAdd(&cnt[d * T + t], 1u);
}

// dinv from REAL (unpadded) counts
__global__ __launch_bounds__(256) void k_dinv(const unsigned* __restrict__ cnt,
                                              float* __restrict__ dinv, int n) {
    int i = blockIdx.x * 256 + threadIdx.x;
    if (i < n) {
        unsigned deg = cnt[i * T + 0] + cnt[i * T + 1] + cnt[i * T + 2] + cnt[i * T + 3];
        dinv[i] = rsqrtf(1.0f + (float)deg);
    }
}

// zero the pad rows (index n) of hs and h4
__global__ __launch_bounds__(64) void k_zpad(__half* __restrict__ hs,
                                             float4* __restrict__ h4, int n) {
    hs[(size_t)n * 64 + threadIdx.x] = __float2half(0.f);
    if (threadIdx.x == 0) h4[n] = make_float4(0.f, 0.f, 0.f, 0.f);
}

// ---- hierarchical exclusive scan over PADDED cell counts -> rowt ----

__global__ __launch_bounds__(256) void k_scan1(const unsigned* __restrict__ cnt,
                                               int* __restrict__ rowt,
                                               unsigned* __restrict__ bsum, int m) {
    __shared__ unsigned t[256];
    int i = blockIdx.x * 256 + threadIdx.x;
    unsigned v = 0;
    if (i < m) { v = cnt[i]; v += (v & 1u); }   // pad to even
    t[threadIdx.x] = v;
    __syncthreads();
    #pragma unroll
    for (int off = 1; off < 256; off <<= 1) {
        unsigned u = (threadIdx.x >= (unsigned)off) ? t[threadIdx.x - off] : 0u;
        __syncthreads();
        t[threadIdx.x] += u;
        __syncthreads();
    }
    if (i < m) rowt[i] = (int)(t[threadIdx.x] - v);
    if (threadIdx.x == 255) bsum[blockIdx.x] = t[255];
}

__global__ __launch_bounds__(256) void k_scan2(unsigned* __restrict__ bsum,
                                               int* __restrict__ rowt,
                                               int nb, int m) {
    __shared__ unsigned t[256];
    unsigned run = 0;
    for (int base = 0; base < nb; base += 256) {
        int i = base + threadIdx.x;
        unsigned v = (i < nb) ? bsum[i] : 0u;
        t[threadIdx.x] = v;
        __syncthreads();
        #pragma unroll
        for (int off = 1; off < 256; off <<= 1) {
            unsigned u = (threadIdx.x >= (unsigned)off) ? t[threadIdx.x - off] : 0u;
            __syncthreads();
            t[threadIdx.x] += u;
            __syncthreads();
        }
        if (i < nb) bsum[i] = run + t[threadIdx.x] - v;
        __syncthreads();
        run += t[255];
        __syncthreads();
    }
    if (threadIdx.x == 0) rowt[m] = (int)run;   // padded total
}

__global__ __launch_bounds__(256) void k_scan3(int* __restrict__ rowt,
                                               const unsigned* __restrict__ bsum, int m) {
    int i = blockIdx.x * 256 + threadIdx.x;
    if (i < m) rowt[i] += (int)bsum[blockIdx.x];
}

// ---- fill (XCD-partitioned by dst range; ushort stores) ----

__global__ __launch_bounds__(256) void k_fill(const int* __restrict__ src,
                                              const int* __restrict__ dst,
                                              const int* __restrict__ rowt,
                                              unsigned* __restrict__ cursor,
                                              unsigned short* __restrict__ csr,
                                              int E, int chunk, int chunkS) {
    int part = blockIdx.x & (NPART - 1);
    int q = blockIdx.x >> 3;
    int lo = part * chunk, hi = lo + chunk;
    for (int e = q * 256 + threadIdx.x; e < E; e += 256 * BPP) {
        int d = dst[e];
        if (d >= lo && d < hi) {
            int s = src[e];
            int cell = d * T + s / chunkS;
            unsigned pos = atomicAdd(&cursor[cell], 1u);
            csr[rowt[cell] + (int)pos] = (unsigned short)s;
        }
    }
}

// write the dummy index n into each odd cell's pad slot
__global__ __launch_bounds__(256) void k_padfix(const unsigned* __restrict__ cnt,
                                                const int* __restrict__ rowt,
                                                unsigned short* __restrict__ csr,
                                                int m, int n) {
    int i = blockIdx.x * 256 + threadIdx.x;
    if (i >= m) return;
    unsigned c = cnt[i];
    if (c & 1u) csr[rowt[i] + (int)c] = (unsigned short)n;
}

// ---- GEMM layer1 (128->64): 16 rows/block, 4 rows/wave, ILP-4 ----

__global__ __launch_bounds__(256) void k_gemm64_f32(const float* __restrict__ x,
                                                    const float* __restrict__ W,
                                                    const float* __restrict__ dinv,
                                                    __half* __restrict__ hs, int n) {
    __shared__ float Wl[128 * 64];
    {
        const f4* Wv = (const f4*)W;
        f4* Wlv = (f4*)Wl;
        for (int idx = threadIdx.x; idx < 128 * 16; idx += 256) Wlv[idx] = Wv[idx];
    }
    __syncthreads();
    int wave = threadIdx.x >> 6, lane = threadIdx.x & 63;
    int i0 = blockIdx.x * 16 + wave * 4;
    if (i0 >= n) return;
    if (i0 + 3 < n) {
        const f4* r0 = (const f4*)(x + (size_t)(i0 + 0) * 128);
        const f4* r1 = (const f4*)(x + (size_t)(i0 + 1) * 128);
        const f4* r2 = (const f4*)(x + (size_t)(i0 + 2) * 128);
        const f4* r3 = (const f4*)(x + (size_t)(i0 + 3) * 128);
        float a0 = 0.f, a1 = 0.f, a2 = 0.f, a3 = 0.f;
        #pragma unroll
        for (int k4 = 0; k4 < 32; ++k4) {
            f4 v0 = __builtin_nontemporal_load(&r0[k4]);
            f4 v1 = __builtin_nontemporal_load(&r1[k4]);
            f4 v2 = __builtin_nontemporal_load(&r2[k4]);
            f4 v3 = __builtin_nontemporal_load(&r3[k4]);
            float w0 = Wl[(k4 * 4 + 0) * 64 + lane];
            float w1 = Wl[(k4 * 4 + 1) * 64 + lane];
            float w2 = Wl[(k4 * 4 + 2) * 64 + lane];
            float w3 = Wl[(k4 * 4 + 3) * 64 + lane];
            a0 += v0.x * w0 + v0.y * w1 + v0.z * w2 + v0.w * w3;
            a1 += v1.x * w0 + v1.y * w1 + v1.z * w2 + v1.w * w3;
            a2 += v2.x * w0 + v2.y * w1 + v2.z * w2 + v2.w * w3;
            a3 += v3.x * w0 + v3.y * w1 + v3.z * w2 + v3.w * w3;
        }
        hs[(size_t)(i0 + 0) * 64 + lane] = __float2half(a0 * dinv[i0 + 0]);
        hs[(size_t)(i0 + 1) * 64 + lane] = __float2half(a1 * dinv[i0 + 1]);
        hs[(size_t)(i0 + 2) * 64 + lane] = __float2half(a2 * dinv[i0 + 2]);
        hs[(size_t)(i0 + 3) * 64 + lane] = __float2half(a3 * dinv[i0 + 3]);
    } else {
        for (int i = i0; i < n && i < i0 + 4; ++i) {
            const f4* r = (const f4*)(x + (size_t)i * 128);
            float acc = 0.f;
            #pragma unroll
            for (int k4 = 0; k4 < 32; ++k4) {
                f4 v = r[k4];
                acc += v.x * Wl[(k4 * 4 + 0) * 64 + lane];
                acc += v.y * Wl[(k4 * 4 + 1) * 64 + lane];
                acc += v.z * Wl[(k4 * 4 + 2) * 64 + lane];
                acc += v.w * Wl[(k4 * 4 + 3) * 64 + lane];
            }
            hs[(size_t)i * 64 + lane] = __float2half(acc * dinv[i]);
        }
    }
}

// ---- GEMM layers 2..8 (64->64 fp16 in): same structure ----

__global__ __launch_bounds__(256) void k_gemm64_f16(const __half* __restrict__ xh,
                                                    const float* __restrict__ W,
                                                    const float* __restrict__ dinv,
                                                    __half* __restrict__ hs, int n) {
    __shared__ float Wl[64 * 64];
    {
        const f4* Wv = (const f4*)W;
        f4* Wlv = (f4*)Wl;
        for (int idx = threadIdx.x; idx < 64 * 16; idx += 256) Wlv[idx] = Wv[idx];
    }
    __syncthreads();
    int wave = threadIdx.x >> 6, lane = threadIdx.x & 63;
    int i0 = blockIdx.x * 16 + wave * 4;
    if (i0 >= n) return;
    if (i0 + 3 < n) {
        const unsigned* r0 = (const unsigned*)(xh + (size_t)(i0 + 0) * 64);
        const unsigned* r1 = (const unsigned*)(xh + (size_t)(i0 + 1) * 64);
        const unsigned* r2 = (const unsigned*)(xh + (size_t)(i0 + 2) * 64);
        const unsigned* r3 = (const unsigned*)(xh + (size_t)(i0 + 3) * 64);
        float a0 = 0.f, a1 = 0.f, a2 = 0.f, a3 = 0.f;
        #pragma unroll
        for (int k2 = 0; k2 < 32; ++k2) {
            unsigned u0 = __builtin_nontemporal_load(&r0[k2]);
            unsigned u1 = __builtin_nontemporal_load(&r1[k2]);
            unsigned u2 = __builtin_nontemporal_load(&r2[k2]);
            unsigned u3 = __builtin_nontemporal_load(&r3[k2]);
            float w0 = Wl[(k2 * 2 + 0) * 64 + lane];
            float w1 = Wl[(k2 * 2 + 1) * 64 + lane];
            float2 v0 = __half22float2(*(__half2*)&u0);
            float2 v1 = __half22float2(*(__half2*)&u1);
            float2 v2 = __half22float2(*(__half2*)&u2);
            float2 v3 = __half22float2(*(__half2*)&u3);
            a0 += v0.x * w0 + v0.y * w1;
            a1 += v1.x * w0 + v1.y * w1;
            a2 += v2.x * w0 + v2.y * w1;
            a3 += v3.x * w0 + v3.y * w1;
        }
        hs[(size_t)(i0 + 0) * 64 + lane] = __float2half(a0 * dinv[i0 + 0]);
        hs[(size_t)(i0 + 1) * 64 + lane] = __float2half(a1 * dinv[i0 + 1]);
        hs[(size_t)(i0 + 2) * 64 + lane] = __float2half(a2 * dinv[i0 + 2]);
        hs[(size_t)(i0 + 3) * 64 + lane] = __float2half(a3 * dinv[i0 + 3]);
    } else {
        for (int i = i0; i < n && i < i0 + 4; ++i) {
            const __half2* r = (const __half2*)(xh + (size_t)i * 64);
            float acc = 0.f;
            #pragma unroll
            for (int k2 = 0; k2 < 32; ++k2) {
                float2 v = __half22float2(r[k2]);
                acc += v.x * Wl[(k2 * 2 + 0) * 64 + lane];
                acc += v.y * Wl[(k2 * 2 + 1) * 64 + lane];
            }
            hs[(size_t)i * 64 + lane] = __float2half(acc * dinv[i]);
        }
    }
}

// ---- small GEMM: h4[i] = (xh[i,:64] @ W[64,4]) * dinv[i] ----
__global__ __launch_bounds__(256) void k_gemm4(const __half* __restrict__ xh,
                                               const float* __restrict__ W,
                                               const float* __restrict__ dinv,
                                               float4* __restrict__ h4, int n) {
    __shared__ float Wl[256];
    for (int idx = threadIdx.x; idx < 256; idx += 256) Wl[idx] = W[idx];
    __syncthreads();
    int i = blockIdx.x * 256 + threadIdx.x;
    if (i >= n) return;
    const __half2* ar = (const __half2*)(xh + (size_t)i * 64);
    float a0 = 0.f, a1 = 0.f, a2 = 0.f, a3 = 0.f;
    #pragma unroll
    for (int k2 = 0; k2 < 32; ++k2) {
        float2 v = __half22float2(ar[k2]);
        int k = k2 * 2;
        a0 += v.x * Wl[k * 4 + 0] + v.y * Wl[(k + 1) * 4 + 0];
        a1 += v.x * Wl[k * 4 + 1] + v.y * Wl[(k + 1) * 4 + 1];
        a2 += v.x * Wl[k * 4 + 2] + v.y * Wl[(k + 1) * 4 + 2];
        a3 += v.x * Wl[k * 4 + 3] + v.y * Wl[(k + 1) * 4 + 3];
    }
    float di = dinv[i];
    h4[i] = make_float4(a0 * di, a1 * di, a2 * di, a3 * di);
}

// ------- agg 64-wide fp16 (R13 form; 16-bit indices, scalar dword pairs) -------
// Row extents [rowt[gw*T], rowt[gw*T+T]) are even; pad slots hold index n
// whose hs row is zeroed -> exact +0 contribution.

__global__ __launch_bounds__(256) void k_agg64h(const __half* __restrict__ hs,
                                                const float* __restrict__ dinv,
                                                const int* __restrict__ rowt,
                                                const unsigned short* __restrict__ csr,
                                                const float* __restrict__ bias,
                                                __half* __restrict__ out, int n) {
    int wid = __builtin_amdgcn_readfirstlane((int)(threadIdx.x >> 6));
    int lane = threadIdx.x & 63;
    int gw = blockIdx.x * 4 + wid;
    if (gw >= n) return;
    float acc = __half2float(hs[(size_t)gw * 64 + lane]);  // self (prescaled)
    int s = rowt[gw * T], e = rowt[gw * T + T];            // both even
    const unsigned* c32 = (const unsigned*)csr;
    int p = s >> 1, pe = e >> 1;
    for (; p + 8 <= pe; p += 8) {                          // 16 edges per iter
        unsigned pr[8];
        #pragma unroll
        for (int j = 0; j < 8; ++j) pr[j] = c32[p + j];
        float v[16];
        #pragma unroll
        for (int j = 0; j < 8; ++j) {
            v[2 * j + 0] = __half2float(hs[(size_t)(pr[j] & 0xFFFFu) * 64 + lane]);
            v[2 * j + 1] = __half2float(hs[(size_t)(pr[j] >> 16) * 64 + lane]);
        }
        float t0 = ((v[0] + v[1]) + (v[2] + v[3])) + ((v[4] + v[5]) + (v[6] + v[7]));
        float t1 = ((v[8] + v[9]) + (v[10] + v[11])) + ((v[12] + v[13]) + (v[14] + v[15]));
        acc += t0 + t1;
    }
    for (; p < pe; ++p) {                                  // even remainder
        unsigned pr = c32[p];
        float v0 = __half2float(hs[(size_t)(pr & 0xFFFFu) * 64 + lane]);
        float v1 = __half2float(hs[(size_t)(pr >> 16) * 64 + lane]);
        acc += v0 + v1;
    }
    acc = acc * dinv[gw] + bias[lane];
    out[(size_t)gw * 64 + lane] = __float2half(fmaxf(acc, 0.f));
}

// ------- agg 4-wide (final): z[d] = (Σ h4[s] + h4[d])*dinv[d] + b3 -------

__global__ __launch_bounds__(256) void k_agg4(const float4* __restrict__ h4,
                                              const float* __restrict__ dinv,
                                              const int* __restrict__ rowt,
                                              const unsigned short* __restrict__ csr,
                                              const float* __restrict__ b3,
                                              float4* __restrict__ z, int n) {
    int i = blockIdx.x * 256 + threadIdx.x;
    if (i >= n) return;
    float4 self = h4[i];
    float a0 = self.x, a1 = self.y, a2 = self.z, a3 = self.w;
    int s = rowt[i * T], e = rowt[i * T + T];
    const unsigned* c32 = (const unsigned*)csr;
    int p = s >> 1, pe = e >> 1;
    for (; p + 2 <= pe; p += 2) {
        unsigned pa = c32[p], pb = c32[p + 1];
        float4 v0 = h4[pa & 0xFFFFu], v1 = h4[pa >> 16];
        float4 v2 = h4[pb & 0xFFFFu], v3 = h4[pb >> 16];
        a0 += v0.x + v1.x + v2.x + v3.x;
        a1 += v0.y + v1.y + v2.y + v3.y;
        a2 += v0.z + v1.z + v2.z + v3.z;
        a3 += v0.w + v1.w + v2.w + v3.w;
    }
    for (; p < pe; ++p) {
        unsigned pr = c32[p];
        float4 v0 = h4[pr & 0xFFFFu], v1 = h4[pr >> 16];
        a0 += v0.x + v1.x; a1 += v0.y + v1.y;
        a2 += v0.z + v1.z; a3 += v0.w + v1.w;
    }
    float di = dinv[i];
    z[i] = make_float4(a0 * di + b3[0], a1 * di + b3[1],
                       a2 * di + b3[2], a3 * di + b3[3]);
}

// ---------------- softmax over node axis (per column, C=4) ----------------

__device__ inline unsigned encf(float f) {
    unsigned u = __float_as_uint(f);
    return (u & 0x80000000u) ? ~u : (u | 0x80000000u);
}
__device__ inline float decf(unsigned e) {
    return (e & 0x80000000u) ? __uint_as_float(e & 0x7FFFFFFFu) : __uint_as_float(~e);
}

__global__ __launch_bounds__(256) void k_max(const float4* __restrict__ z,
                                             unsigned* __restrict__ gmax, int n) {
    float m0 = -FLT_MAX, m1 = -FLT_MAX, m2 = -FLT_MAX, m3 = -FLT_MAX;
    for (int i = blockIdx.x * 256 + threadIdx.x; i < n; i += gridDim.x * 256) {
        float4 v = z[i];
        m0 = fmaxf(m0, v.x); m1 = fmaxf(m1, v.y);
        m2 = fmaxf(m2, v.z); m3 = fmaxf(m3, v.w);
    }
    #pragma unroll
    for (int off = 32; off; off >>= 1) {
        m0 = fmaxf(m0, __shfl_xor(m0, off));
        m1 = fmaxf(m1, __shfl_xor(m1, off));
        m2 = fmaxf(m2, __shfl_xor(m2, off));
        m3 = fmaxf(m3, __shfl_xor(m3, off));
    }
    if ((threadIdx.x & 63) == 0) {
        atomicMax(&gmax[0], encf(m0));
        atomicMax(&gmax[1], encf(m1));
        atomicMax(&gmax[2], encf(m2));
        atomicMax(&gmax[3], encf(m3));
    }
}

__global__ __launch_bounds__(256) void k_exp(const float4* __restrict__ z,
                                             float4* __restrict__ out,
                                             const unsigned* __restrict__ gmax,
                                             float* __restrict__ gsum, int n) {
    float M0 = decf(gmax[0]), M1 = decf(gmax[1]), M2 = decf(gmax[2]), M3 = decf(gmax[3]);
    float s0 = 0.f, s1 = 0.f, s2 = 0.f, s3 = 0.f;
    for (int i = blockIdx.x * 256 + threadIdx.x; i < n; i += gridDim.x * 256) {
        float4 v = z[i];
        float4 e;
        e.x = expf(v.x - M0); e.y = expf(v.y - M1);
        e.z = expf(v.z - M2); e.w = expf(v.w - M3);
        out[i] = e;
        s0 += e.x; s1 += e.y; s2 += e.z; s3 += e.w;
    }
    #pragma unroll
    for (int off = 32; off; off >>= 1) {
        s0 += __shfl_xor(s0, off);
        s1 += __shfl_xor(s1, off);
        s2 += __shfl_xor(s2, off);
        s3 += __shfl_xor(s3, off);
    }
    if ((threadIdx.x & 63) == 0) {
        atomicAdd(&gsum[0], s0);
        atomicAdd(&gsum[1], s1);
        atomicAdd(&gsum[2], s2);
        atomicAdd(&gsum[3], s3);
    }
}

__global__ __launch_bounds__(256) void k_norm(float4* __restrict__ out,
                                              const float* __restrict__ gsum, int n) {
    float r0 = 1.f / gsum[0], r1 = 1.f / gsum[1], r2 = 1.f / gsum[2], r3 = 1.f / gsum[3];
    for (int i = blockIdx.x * 256 + threadIdx.x; i < n; i += gridDim.x * 256) {
        float4 v = out[i];
        v.x *= r0; v.y *= r1; v.z *= r2; v.w *= r3;
        out[i] = v;
    }
}

// ---------------------------------------------------------------------------

extern "C" void kernel_launch(void* const* d_in, const int* in_sizes, int n_in,
                              void* d_out, int out_size, void* d_ws, size_t ws_size,
                              hipStream_t stream) {
    const float* x0 = (const float*)d_in[0];
    const int* ei = (const int*)d_in[1];
    const float* W1 = (const float*)d_in[2];
    const float* b1 = (const float*)d_in[3];
    const float* W2 = (const float*)d_in[4];
    const float* b2 = (const float*)d_in[5];
    const float* W3 = (const float*)d_in[6];
    const float* b3 = (const float*)d_in[7];

    const int n = in_sizes[0] / 128;   // 50000
    const int E = in_sizes[1] / 2;     // 1600000
    const int* src = ei;
    const int* dst = ei + E;
    const int chunk = (n + NPART - 1) / NPART;   // dst partition size
    const int chunkS = (n + T - 1) / T;          // src tile size
    const int m = n * T;                         // (dst, tile) cells

    char* ws = (char*)d_ws;
    size_t off = 0;
    auto alloc = [&](size_t bytes) -> void* {
        void* p = (void*)(ws + off);
        off = (off + bytes + 255) & ~(size_t)255;
        return p;
    };

    // zeroed region first (cnt, cursor, gmax, gsum)
    unsigned* cnt    = (unsigned*)alloc((size_t)m * 4);
    unsigned* cursor = (unsigned*)alloc((size_t)m * 4);
    unsigned* gmax   = (unsigned*)alloc(16);
    float*    gsum   = (float*)alloc(16);
    size_t zero_bytes = off;

    float* dinv      = (float*)alloc((size_t)n * 4);
    int*   rowt      = (int*)alloc((size_t)(m + 1) * 4);
    unsigned* bsum   = (unsigned*)alloc(1024 * 4);
    unsigned short* csr = (unsigned short*)alloc(((size_t)E + m + 2) * 2);
    __half* hbuf     = (__half*)alloc((size_t)(n + 1) * 64 * 2);  // +1 pad row
    __half* xbuf     = (__half*)alloc((size_t)n * 64 * 2);
    float4* h4buf    = (float4*)alloc((size_t)(n + 1) * 16);      // +1 pad row
    float4* zbuf     = (float4*)alloc((size_t)n * 16);

    hipMemsetAsync(cnt, 0, zero_bytes, stream);

    const int nbN = (n + 255) / 256;
    const int nbE = (E + 255) / 256;
    const int nbM = (m + 255) / 256;

    // CSR build: histogram -> padded scan -> dinv -> fill -> padfix
    k_zpad<<<1, 64, 0, stream>>>(hbuf, h4buf, n);
    k_count<<<nbE, 256, 0, stream>>>(src, dst, cnt, E, chunkS);
    k_scan1<<<nbM, 256, 0, stream>>>(cnt, rowt, bsum, m);
    k_scan2<<<1, 256, 0, stream>>>(bsum, rowt, nbM, m);
    k_scan3<<<nbM, 256, 0, stream>>>(rowt, bsum, m);
    k_dinv<<<nbN, 256, 0, stream>>>(cnt, dinv, n);
    k_fill<<<NPART * BPP, 256, 0, stream>>>(src, dst, rowt, cursor, csr, E, chunk, chunkS);
    k_padfix<<<nbM, 256, 0, stream>>>(cnt, rowt, csr, m, n);

    const int nbG = (n + 15) / 16;        // gemm blocks (16 rows/block)
    const int nbA = (n + 3) / 4;          // agg blocks (4 waves/block)

    // layer 1: 128 -> 64 (fp32 input)
    k_gemm64_f32<<<nbG, 256, 0, stream>>>(x0, W1, dinv, hbuf, n);
    k_agg64h<<<nbA, 256, 0, stream>>>(hbuf, dinv, rowt, csr, b1, xbuf, n);

    // layers 2..8: 64 -> 64, shared W2 (fp16 activations)
    for (int l = 0; l < 7; ++l) {
        k_gemm64_f16<<<nbG, 256, 0, stream>>>(xbuf, W2, dinv, hbuf, n);
        k_agg64h<<<nbA, 256, 0, stream>>>(hbuf, dinv, rowt, csr, b2, xbuf, n);
    }

    // layer 9: gemm to 4 features first, then 4-wide agg (fp32)
    k_gemm4<<<nbN, 256, 0, stream>>>(xbuf, W3, dinv, h4buf, n);
    k_agg4<<<nbN, 256, 0, stream>>>(h4buf, dinv, rowt, csr, b3, zbuf, n);

    // softmax over node axis
    k_max<<<256, 256, 0, stream>>>(zbuf, gmax, n);
    k_exp<<<256, 256, 0, stream>>>(zbuf, (float4*)d_out, gmax, gsum, n);
    k_norm<<<256, 256, 0, stream>>>((float4*)d_out, gsum, n);
}

// Round 15
// 829.578 us; speedup vs baseline: 1.0291x; 1.0291x over previous
//
#include <hip/hip_runtime.h>
#include <hip/hip_fp16.h>
#include <math.h>
#include <float.h>

// ---------------------------------------------------------------------------
// GCN on MI355X. N=50000, E=1.6M, widths 128 -> 64 (x8) -> 4.
// R14 structure + FP8(e4m3) gathered activations: hs rows are 64B = ONE cache
// line per edge gather (fp16 was 2). GEMM epilogue encodes hs=e4m3(h*dinv*16);
// agg decodes via exact bit trick (f16(bits<<7)*256), folds /16 into the dst
// dinv. xbuf (GEMM input) stays fp16; accumulation fp32; layer 9 fp32.
// CSR: 16-bit indices, (dst,src_tile) grouped, cells padded even with dummy
// index n -> zeroed pad row (exact +0). Fill XCD-partitioned by dst.
// ---------------------------------------------------------------------------

#define NPART 8
#define BPP   104     // blocks per partition for fill
#define T     4       // src tiles

typedef float f4 __attribute__((ext_vector_type(4)));

// ---- fp8 e4m3 (OCP) helpers: encode f32->byte, decode byte->f32 ----
__device__ inline unsigned char f32_to_e4m3(float x) {
    unsigned short h = __half_as_ushort(__float2half(x * 0.00390625f)); // /256
    unsigned s = (h >> 8) & 0x80u;
    unsigned mag = h & 0x7FFFu;
    unsigned r = (mag + 0x40u) >> 7;         // round to 3-bit mantissa grid
    if (r > 0x7Eu) r = 0x7Eu;                // saturate to 448
    return (unsigned char)(s | r);
}
__device__ inline float e4m3_to_f32(unsigned char b) {
    unsigned short h = (unsigned short)(((b & 0x80u) << 8) | ((b & 0x7Fu) << 7));
    return __half2float(__ushort_as_half(h)) * 256.f;  // exact, subnormal-safe
}
#define FP8_SCALE   16.f
#define FP8_DESCALE 0.0625f

// ---------------- (dst, src_tile) histogram ----------------

__global__ __launch_bounds__(256) void k_count(const int* __restrict__ src,
                                               const int* __restrict__ dst,
                                               unsigned* __restrict__ cnt,
                                               int E, int chunkS) {
    int e = blockIdx.x * 256 + threadIdx.x;
    if (e >= E) return;
    int d = dst[e];
    int t = src[e] / chunkS;
    atomicAdd(&cnt[d * T + t], 1u);
}

__global__ __launch_bounds__(256) void k_dinv(const unsigned* __restrict__ cnt,
                                              float* __restrict__ dinv, int n) {
    int i = blockIdx.x * 256 + threadIdx.x;
    if (i < n) {
        unsigned deg = cnt[i * T + 0] + cnt[i * T + 1] + cnt[i * T + 2] + cnt[i * T + 3];
        dinv[i] = rsqrtf(1.0f + (float)deg);
    }
}

// zero the pad rows (index n) of hs (fp8) and h4
__global__ __launch_bounds__(64) void k_zpad(unsigned char* __restrict__ hs,
                                             float4* __restrict__ h4, int n) {
    hs[(size_t)n * 64 + threadIdx.x] = 0;
    if (threadIdx.x == 0) h4[n] = make_float4(0.f, 0.f, 0.f, 0.f);
}

// ---- hierarchical exclusive scan over PADDED cell counts -> rowt ----

__global__ __launch_bounds__(256) void k_scan1(const unsigned* __restrict__ cnt,
                                               int* __restrict__ rowt,
                                               unsigned* __restrict__ bsum, int m) {
    __shared__ unsigned t[256];
    int i = blockIdx.x * 256 + threadIdx.x;
    unsigned v = 0;
    if (i < m) { v = cnt[i]; v += (v & 1u); }   // pad to even
    t[threadIdx.x] = v;
    __syncthreads();
    #pragma unroll
    for (int off = 1; off < 256; off <<= 1) {
        unsigned u = (threadIdx.x >= (unsigned)off) ? t[threadIdx.x - off] : 0u;
        __syncthreads();
        t[threadIdx.x] += u;
        __syncthreads();
    }
    if (i < m) rowt[i] = (int)(t[threadIdx.x] - v);
    if (threadIdx.x == 255) bsum[blockIdx.x] = t[255];
}

__global__ __launch_bounds__(256) void k_scan2(unsigned* __restrict__ bsum,
                                               int* __restrict__ rowt,
                                               int nb, int m) {
    __shared__ unsigned t[256];
    unsigned run = 0;
    for (int base = 0; base < nb; base += 256) {
        int i = base + threadIdx.x;
        unsigned v = (i < nb) ? bsum[i] : 0u;
        t[threadIdx.x] = v;
        __syncthreads();
        #pragma unroll
        for (int off = 1; off < 256; off <<= 1) {
            unsigned u = (threadIdx.x >= (unsigned)off) ? t[threadIdx.x - off] : 0u;
            __syncthreads();
            t[threadIdx.x] += u;
            __syncthreads();
        }
        if (i < nb) bsum[i] = run + t[threadIdx.x] - v;
        __syncthreads();
        run += t[255];
        __syncthreads();
    }
    if (threadIdx.x == 0) rowt[m] = (int)run;
}

__global__ __launch_bounds__(256) void k_scan3(int* __restrict__ rowt,
                                               const unsigned* __restrict__ bsum, int m) {
    int i = blockIdx.x * 256 + threadIdx.x;
    if (i < m) rowt[i] += (int)bsum[blockIdx.x];
}

// ---- fill (XCD-partitioned by dst range; ushort stores) ----

__global__ __launch_bounds__(256) void k_fill(const int* __restrict__ src,
                                              const int* __restrict__ dst,
                                              const int* __restrict__ rowt,
                                              unsigned* __restrict__ cursor,
                                              unsigned short* __restrict__ csr,
                                              int E, int chunk, int chunkS) {
    int part = blockIdx.x & (NPART - 1);
    int q = blockIdx.x >> 3;
    int lo = part * chunk, hi = lo + chunk;
    for (int e = q * 256 + threadIdx.x; e < E; e += 256 * BPP) {
        int d = dst[e];
        if (d >= lo && d < hi) {
            int s = src[e];
            int cell = d * T + s / chunkS;
            unsigned pos = atomicAdd(&cursor[cell], 1u);
            csr[rowt[cell] + (int)pos] = (unsigned short)s;
        }
    }
}

__global__ __launch_bounds__(256) void k_padfix(const unsigned* __restrict__ cnt,
                                                const int* __restrict__ rowt,
                                                unsigned short* __restrict__ csr,
                                                int m, int n) {
    int i = blockIdx.x * 256 + threadIdx.x;
    if (i >= m) return;
    unsigned c = cnt[i];
    if (c & 1u) csr[rowt[i] + (int)c] = (unsigned short)n;
}

// ---- GEMM layer1 (128->64): 16 rows/block, 4 rows/wave, ILP-4, fp8 out ----

__global__ __launch_bounds__(256) void k_gemm64_f32(const float* __restrict__ x,
                                                    const float* __restrict__ W,
                                                    const float* __restrict__ dinv,
                                                    unsigned char* __restrict__ hs, int n) {
    __shared__ float Wl[128 * 64];
    {
        const f4* Wv = (const f4*)W;
        f4* Wlv = (f4*)Wl;
        for (int idx = threadIdx.x; idx < 128 * 16; idx += 256) Wlv[idx] = Wv[idx];
    }
    __syncthreads();
    int wave = threadIdx.x >> 6, lane = threadIdx.x & 63;
    int i0 = blockIdx.x * 16 + wave * 4;
    if (i0 >= n) return;
    if (i0 + 3 < n) {
        const f4* r0 = (const f4*)(x + (size_t)(i0 + 0) * 128);
        const f4* r1 = (const f4*)(x + (size_t)(i0 + 1) * 128);
        const f4* r2 = (const f4*)(x + (size_t)(i0 + 2) * 128);
        const f4* r3 = (const f4*)(x + (size_t)(i0 + 3) * 128);
        float a0 = 0.f, a1 = 0.f, a2 = 0.f, a3 = 0.f;
        #pragma unroll
        for (int k4 = 0; k4 < 32; ++k4) {
            f4 v0 = __builtin_nontemporal_load(&r0[k4]);
            f4 v1 = __builtin_nontemporal_load(&r1[k4]);
            f4 v2 = __builtin_nontemporal_load(&r2[k4]);
            f4 v3 = __builtin_nontemporal_load(&r3[k4]);
            float w0 = Wl[(k4 * 4 + 0) * 64 + lane];
            float w1 = Wl[(k4 * 4 + 1) * 64 + lane];
            float w2 = Wl[(k4 * 4 + 2) * 64 + lane];
            float w3 = Wl[(k4 * 4 + 3) * 64 + lane];
            a0 += v0.x * w0 + v0.y * w1 + v0.z * w2 + v0.w * w3;
            a1 += v1.x * w0 + v1.y * w1 + v1.z * w2 + v1.w * w3;
            a2 += v2.x * w0 + v2.y * w1 + v2.z * w2 + v2.w * w3;
            a3 += v3.x * w0 + v3.y * w1 + v3.z * w2 + v3.w * w3;
        }
        hs[(size_t)(i0 + 0) * 64 + lane] = f32_to_e4m3(a0 * dinv[i0 + 0] * FP8_SCALE);
        hs[(size_t)(i0 + 1) * 64 + lane] = f32_to_e4m3(a1 * dinv[i0 + 1] * FP8_SCALE);
        hs[(size_t)(i0 + 2) * 64 + lane] = f32_to_e4m3(a2 * dinv[i0 + 2] * FP8_SCALE);
        hs[(size_t)(i0 + 3) * 64 + lane] = f32_to_e4m3(a3 * dinv[i0 + 3] * FP8_SCALE);
    } else {
        for (int i = i0; i < n && i < i0 + 4; ++i) {
            const f4* r = (const f4*)(x + (size_t)i * 128);
            float acc = 0.f;
            #pragma unroll
            for (int k4 = 0; k4 < 32; ++k4) {
                f4 v = r[k4];
                acc += v.x * Wl[(k4 * 4 + 0) * 64 + lane];
                acc += v.y * Wl[(k4 * 4 + 1) * 64 + lane];
                acc += v.z * Wl[(k4 * 4 + 2) * 64 + lane];
                acc += v.w * Wl[(k4 * 4 + 3) * 64 + lane];
            }
            hs[(size_t)i * 64 + lane] = f32_to_e4m3(acc * dinv[i] * FP8_SCALE);
        }
    }
}

// ---- GEMM layers 2..8 (64->64 fp16 in, fp8 out) ----

__global__ __launch_bounds__(256) void k_gemm64_f16(const __half* __restrict__ xh,
                                                    const float* __restrict__ W,
                                                    const float* __restrict__ dinv,
                                                    unsigned char* __restrict__ hs, int n) {
    __shared__ float Wl[64 * 64];
    {
        const f4* Wv = (const f4*)W;
        f4* Wlv = (f4*)Wl;
        for (int idx = threadIdx.x; idx < 64 * 16; idx += 256) Wlv[idx] = Wv[idx];
    }
    __syncthreads();
    int wave = threadIdx.x >> 6, lane = threadIdx.x & 63;
    int i0 = blockIdx.x * 16 + wave * 4;
    if (i0 >= n) return;
    if (i0 + 3 < n) {
        const unsigned* r0 = (const unsigned*)(xh + (size_t)(i0 + 0) * 64);
        const unsigned* r1 = (const unsigned*)(xh + (size_t)(i0 + 1) * 64);
        const unsigned* r2 = (const unsigned*)(xh + (size_t)(i0 + 2) * 64);
        const unsigned* r3 = (const unsigned*)(xh + (size_t)(i0 + 3) * 64);
        float a0 = 0.f, a1 = 0.f, a2 = 0.f, a3 = 0.f;
        #pragma unroll
        for (int k2 = 0; k2 < 32; ++k2) {
            unsigned u0 = __builtin_nontemporal_load(&r0[k2]);
            unsigned u1 = __builtin_nontemporal_load(&r1[k2]);
            unsigned u2 = __builtin_nontemporal_load(&r2[k2]);
            unsigned u3 = __builtin_nontemporal_load(&r3[k2]);
            float w0 = Wl[(k2 * 2 + 0) * 64 + lane];
            float w1 = Wl[(k2 * 2 + 1) * 64 + lane];
            float2 v0 = __half22float2(*(__half2*)&u0);
            float2 v1 = __half22float2(*(__half2*)&u1);
            float2 v2 = __half22float2(*(__half2*)&u2);
            float2 v3 = __half22float2(*(__half2*)&u3);
            a0 += v0.x * w0 + v0.y * w1;
            a1 += v1.x * w0 + v1.y * w1;
            a2 += v2.x * w0 + v2.y * w1;
            a3 += v3.x * w0 + v3.y * w1;
        }
        hs[(size_t)(i0 + 0) * 64 + lane] = f32_to_e4m3(a0 * dinv[i0 + 0] * FP8_SCALE);
        hs[(size_t)(i0 + 1) * 64 + lane] = f32_to_e4m3(a1 * dinv[i0 + 1] * FP8_SCALE);
        hs[(size_t)(i0 + 2) * 64 + lane] = f32_to_e4m3(a2 * dinv[i0 + 2] * FP8_SCALE);
        hs[(size_t)(i0 + 3) * 64 + lane] = f32_to_e4m3(a3 * dinv[i0 + 3] * FP8_SCALE);
    } else {
        for (int i = i0; i < n && i < i0 + 4; ++i) {
            const __half2* r = (const __half2*)(xh + (size_t)i * 64);
            float acc = 0.f;
            #pragma unroll
            for (int k2 = 0; k2 < 32; ++k2) {
                float2 v = __half22float2(r[k2]);
                acc += v.x * Wl[(k2 * 2 + 0) * 64 + lane];
                acc += v.y * Wl[(k2 * 2 + 1) * 64 + lane];
            }
            hs[(size_t)i * 64 + lane] = f32_to_e4m3(acc * dinv[i] * FP8_SCALE);
        }
    }
}

// ---- small GEMM: h4[i] = (xh[i,:64] @ W[64,4]) * dinv[i] (fp32 out) ----
__global__ __launch_bounds__(256) void k_gemm4(const __half* __restrict__ xh,
                                               const float* __restrict__ W,
                                               const float* __restrict__ dinv,
                                               float4* __restrict__ h4, int n) {
    __shared__ float Wl[256];
    for (int idx = threadIdx.x; idx < 256; idx += 256) Wl[idx] = W[idx];
    __syncthreads();
    int i = blockIdx.x * 256 + threadIdx.x;
    if (i >= n) return;
    const __half2* ar = (const __half2*)(xh + (size_t)i * 64);
    float a0 = 0.f, a1 = 0.f, a2 = 0.f, a3 = 0.f;
    #pragma unroll
    for (int k2 = 0; k2 < 32; ++k2) {
        float2 v = __half22float2(ar[k2]);
        int k = k2 * 2;
        a0 += v.x * Wl[k * 4 + 0] + v.y * Wl[(k + 1) * 4 + 0];
        a1 += v.x * Wl[k * 4 + 1] + v.y * Wl[(k + 1) * 4 + 1];
        a2 += v.x * Wl[k * 4 + 2] + v.y * Wl[(k + 1) * 4 + 2];
        a3 += v.x * Wl[k * 4 + 3] + v.y * Wl[(k + 1) * 4 + 3];
    }
    float di = dinv[i];
    h4[i] = make_float4(a0 * di, a1 * di, a2 * di, a3 * di);
}

// ------- agg 64-wide fp8: 1 cache line per edge gather -------
// wave per node (scalar index loads); out fp16; /FP8_SCALE folded into dinv.

__global__ __launch_bounds__(256) void k_agg64h(const unsigned char* __restrict__ hs,
                                                const float* __restrict__ dinv,
                                                const int* __restrict__ rowt,
                                                const unsigned short* __restrict__ csr,
                                                const float* __restrict__ bias,
                                                __half* __restrict__ out, int n) {
    int wid = __builtin_amdgcn_readfirstlane((int)(threadIdx.x >> 6));
    int lane = threadIdx.x & 63;
    int gw = blockIdx.x * 4 + wid;
    if (gw >= n) return;
    float acc = e4m3_to_f32(hs[(size_t)gw * 64 + lane]);   // self (prescaled)
    int s = rowt[gw * T], e = rowt[gw * T + T];            // both even
    const unsigned* c32 = (const unsigned*)csr;
    int p = s >> 1, pe = e >> 1;
    for (; p + 8 <= pe; p += 8) {                          // 16 edges per iter
        unsigned pr[8];
        #pragma unroll
        for (int j = 0; j < 8; ++j) pr[j] = c32[p + j];
        float v[16];
        #pragma unroll
        for (int j = 0; j < 8; ++j) {
            v[2 * j + 0] = e4m3_to_f32(hs[(size_t)(pr[j] & 0xFFFFu) * 64 + lane]);
            v[2 * j + 1] = e4m3_to_f32(hs[(size_t)(pr[j] >> 16) * 64 + lane]);
        }
        float t0 = ((v[0] + v[1]) + (v[2] + v[3])) + ((v[4] + v[5]) + (v[6] + v[7]));
        float t1 = ((v[8] + v[9]) + (v[10] + v[11])) + ((v[12] + v[13]) + (v[14] + v[15]));
        acc += t0 + t1;
    }
    for (; p < pe; ++p) {
        unsigned pr = c32[p];
        float v0 = e4m3_to_f32(hs[(size_t)(pr & 0xFFFFu) * 64 + lane]);
        float v1 = e4m3_to_f32(hs[(size_t)(pr >> 16) * 64 + lane]);
        acc += v0 + v1;
    }
    acc = acc * (dinv[gw] * FP8_DESCALE) + bias[lane];
    out[(size_t)gw * 64 + lane] = __float2half(fmaxf(acc, 0.f));
}

// ------- agg 4-wide (final, fp32): z[d] = (Σ h4[s] + h4[d])*dinv[d] + b3 -------

__global__ __launch_bounds__(256) void k_agg4(const float4* __restrict__ h4,
                                              const float* __restrict__ dinv,
                                              const int* __restrict__ rowt,
                                              const unsigned short* __restrict__ csr,
                                              const float* __restrict__ b3,
                                              float4* __restrict__ z, int n) {
    int i = blockIdx.x * 256 + threadIdx.x;
    if (i >= n) return;
    float4 self = h4[i];
    float a0 = self.x, a1 = self.y, a2 = self.z, a3 = self.w;
    int s = rowt[i * T], e = rowt[i * T + T];
    const unsigned* c32 = (const unsigned*)csr;
    int p = s >> 1, pe = e >> 1;
    for (; p + 2 <= pe; p += 2) {
        unsigned pa = c32[p], pb = c32[p + 1];
        float4 v0 = h4[pa & 0xFFFFu], v1 = h4[pa >> 16];
        float4 v2 = h4[pb & 0xFFFFu], v3 = h4[pb >> 16];
        a0 += v0.x + v1.x + v2.x + v3.x;
        a1 += v0.y + v1.y + v2.y + v3.y;
        a2 += v0.z + v1.z + v2.z + v3.z;
        a3 += v0.w + v1.w + v2.w + v3.w;
    }
    for (; p < pe; ++p) {
        unsigned pr = c32[p];
        float4 v0 = h4[pr & 0xFFFFu], v1 = h4[pr >> 16];
        a0 += v0.x + v1.x; a1 += v0.y + v1.y;
        a2 += v0.z + v1.z; a3 += v0.w + v1.w;
    }
    float di = dinv[i];
    z[i] = make_float4(a0 * di + b3[0], a1 * di + b3[1],
                       a2 * di + b3[2], a3 * di + b3[3]);
}

// ---------------- softmax over node axis (per column, C=4) ----------------

__device__ inline unsigned encf(float f) {
    unsigned u = __float_as_uint(f);
    return (u & 0x80000000u) ? ~u : (u | 0x80000000u);
}
__device__ inline float decf(unsigned e) {
    return (e & 0x80000000u) ? __uint_as_float(e & 0x7FFFFFFFu) : __uint_as_float(~e);
}

__global__ __launch_bounds__(256) void k_max(const float4* __restrict__ z,
                                             unsigned* __restrict__ gmax, int n) {
    float m0 = -FLT_MAX, m1 = -FLT_MAX, m2 = -FLT_MAX, m3 = -FLT_MAX;
    for (int i = blockIdx.x * 256 + threadIdx.x; i < n; i += gridDim.x * 256) {
        float4 v = z[i];
        m0 = fmaxf(m0, v.x); m1 = fmaxf(m1, v.y);
        m2 = fmaxf(m2, v.z); m3 = fmaxf(m3, v.w);
    }
    #pragma unroll
    for (int off = 32; off; off >>= 1) {
        m0 = fmaxf(m0, __shfl_xor(m0, off));
        m1 = fmaxf(m1, __shfl_xor(m1, off));
        m2 = fmaxf(m2, __shfl_xor(m2, off));
        m3 = fmaxf(m3, __shfl_xor(m3, off));
    }
    if ((threadIdx.x & 63) == 0) {
        atomicMax(&gmax[0], encf(m0));
        atomicMax(&gmax[1], encf(m1));
        atomicMax(&gmax[2], encf(m2));
        atomicMax(&gmax[3], encf(m3));
    }
}

__global__ __launch_bounds__(256) void k_exp(const float4* __restrict__ z,
                                             float4* __restrict__ out,
                                             const unsigned* __restrict__ gmax,
                                             float* __restrict__ gsum, int n) {
    float M0 = decf(gmax[0]), M1 = decf(gmax[1]), M2 = decf(gmax[2]), M3 = decf(gmax[3]);
    float s0 = 0.f, s1 = 0.f, s2 = 0.f, s3 = 0.f;
    for (int i = blockIdx.x * 256 + threadIdx.x; i < n; i += gridDim.x * 256) {
        float4 v = z[i];
        float4 e;
        e.x = expf(v.x - M0); e.y = expf(v.y - M1);
        e.z = expf(v.z - M2); e.w = expf(v.w - M3);
        out[i] = e;
        s0 += e.x; s1 += e.y; s2 += e.z; s3 += e.w;
    }
    #pragma unroll
    for (int off = 32; off; off >>= 1) {
        s0 += __shfl_xor(s0, off);
        s1 += __shfl_xor(s1, off);
        s2 += __shfl_xor(s2, off);
        s3 += __shfl_xor(s3, off);
    }
    if ((threadIdx.x & 63) == 0) {
        atomicAdd(&gsum[0], s0);
        atomicAdd(&gsum[1], s1);
        atomicAdd(&gsum[2], s2);
        atomicAdd(&gsum[3], s3);
    }
}

__global__ __launch_bounds__(256) void k_norm(float4* __restrict__ out,
                                              const float* __restrict__ gsum, int n) {
    float r0 = 1.f / gsum[0], r1 = 1.f / gsum[1], r2 = 1.f / gsum[2], r3 = 1.f / gsum[3];
    for (int i = blockIdx.x * 256 + threadIdx.x; i < n; i += gridDim.x * 256) {
        float4 v = out[i];
        v.x *= r0; v.y *= r1; v.z *= r2; v.w *= r3;
        out[i] = v;
    }
}

// ---------------------------------------------------------------------------

extern "C" void kernel_launch(void* const* d_in, const int* in_sizes, int n_in,
                              void* d_out, int out_size, void* d_ws, size_t ws_size,
                              hipStream_t stream) {
    const float* x0 = (const float*)d_in[0];
    const int* ei = (const int*)d_in[1];
    const float* W1 = (const float*)d_in[2];
    const float* b1 = (const float*)d_in[3];
    const float* W2 = (const float*)d_in[4];
    const float* b2 = (const float*)d_in[5];
    const float* W3 = (const float*)d_in[6];
    const float* b3 = (const float*)d_in[7];

    const int n = in_sizes[0] / 128;   // 50000
    const int E = in_sizes[1] / 2;     // 1600000
    const int* src = ei;
    const int* dst = ei + E;
    const int chunk = (n + NPART - 1) / NPART;   // dst partition size
    const int chunkS = (n + T - 1) / T;          // src tile size
    const int m = n * T;                         // (dst, tile) cells

    char* ws = (char*)d_ws;
    size_t off = 0;
    auto alloc = [&](size_t bytes) -> void* {
        void* p = (void*)(ws + off);
        off = (off + bytes + 255) & ~(size_t)255;
        return p;
    };

    // zeroed region first (cnt, cursor, gmax, gsum)
    unsigned* cnt    = (unsigned*)alloc((size_t)m * 4);
    unsigned* cursor = (unsigned*)alloc((size_t)m * 4);
    unsigned* gmax   = (unsigned*)alloc(16);
    float*    gsum   = (float*)alloc(16);
    size_t zero_bytes = off;

    float* dinv      = (float*)alloc((size_t)n * 4);
    int*   rowt      = (int*)alloc((size_t)(m + 1) * 4);
    unsigned* bsum   = (unsigned*)alloc(1024 * 4);
    unsigned short* csr = (unsigned short*)alloc(((size_t)E + m + 2) * 2);
    unsigned char* hbuf = (unsigned char*)alloc((size_t)(n + 1) * 64);  // fp8, +pad row
    __half* xbuf     = (__half*)alloc((size_t)n * 64 * 2);
    float4* h4buf    = (float4*)alloc((size_t)(n + 1) * 16);            // +pad row
    float4* zbuf     = (float4*)alloc((size_t)n * 16);

    hipMemsetAsync(cnt, 0, zero_bytes, stream);

    const int nbN = (n + 255) / 256;
    const int nbE = (E + 255) / 256;
    const int nbM = (m + 255) / 256;

    // CSR build: histogram -> padded scan -> dinv -> fill -> padfix
    k_zpad<<<1, 64, 0, stream>>>(hbuf, h4buf, n);
    k_count<<<nbE, 256, 0, stream>>>(src, dst, cnt, E, chunkS);
    k_scan1<<<nbM, 256, 0, stream>>>(cnt, rowt, bsum, m);
    k_scan2<<<1, 256, 0, stream>>>(bsum, rowt, nbM, m);
    k_scan3<<<nbM, 256, 0, stream>>>(rowt, bsum, m);
    k_dinv<<<nbN, 256, 0, stream>>>(cnt, dinv, n);
    k_fill<<<NPART * BPP, 256, 0, stream>>>(src, dst, rowt, cursor, csr, E, chunk, chunkS);
    k_padfix<<<nbM, 256, 0, stream>>>(cnt, rowt, csr, m, n);

    const int nbG = (n + 15) / 16;        // gemm blocks (16 rows/block)
    const int nbA = (n + 3) / 4;          // agg blocks (4 waves/block)

    // layer 1: 128 -> 64 (fp32 input)
    k_gemm64_f32<<<nbG, 256, 0, stream>>>(x0, W1, dinv, hbuf, n);
    k_agg64h<<<nbA, 256, 0, stream>>>(hbuf, dinv, rowt, csr, b1, xbuf, n);

    // layers 2..8: 64 -> 64, shared W2 (fp16 activations, fp8 gathered hs)
    for (int l = 0; l < 7; ++l) {
        k_gemm64_f16<<<nbG, 256, 0, stream>>>(xbuf, W2, dinv, hbuf, n);
        k_agg64h<<<nbA, 256, 0, stream>>>(hbuf, dinv, rowt, csr, b2, xbuf, n);
    }

    // layer 9: gemm to 4 features first, then 4-wide agg (fp32)
    k_gemm4<<<nbN, 256, 0, stream>>>(xbuf, W3, dinv, h4buf, n);
    k_agg4<<<nbN, 256, 0, stream>>>(h4buf, dinv, rowt, csr, b3, zbuf, n);

    // softmax over node axis
    k_max<<<256, 256, 0, stream>>>(zbuf, gmax, n);
    k_exp<<<256, 256, 0, stream>>>(zbuf, (float4*)d_out, gmax, gsum, n);
    k_norm<<<256, 256, 0, stream>>>((float4*)d_out, gsum, n);
}